// Round 6
// baseline (115.726 us; speedup 1.0000x reference)
//
#include <hip/hip_runtime.h>
#include <stdint.h>

#define BQ 4
#define CC 3
#define MM 4096
#define NN 8192
#define KK 16
#define NP_OFF (BQ*CC*MM*KK)    // coords first, then indices
#define BLOCK 512
#define RPW 4                    // rows per wave (= rows per group)
#define GROUPS 4                 // row groups per block
#define ROWS (GROUPS*RPW)        // 16 rows per block
#define CHUNK 1024               // points per LDS buffer (16 KB of float4)
#define NCH (NN/CHUNK)           // 8
#define CST (CHUNK/64)           // 16 wave-steps per chunk
#define HST (CST/2)              // 8 steps per half-wave
#define EPSD 1e-4f               // dotf-space slack (folded vs reference ~1e-6)

__device__ __forceinline__ float rfl(float x) {
    return __uint_as_float((unsigned)__builtin_amdgcn_readfirstlane((int)__float_as_uint(x)));
}

__global__ __launch_bounds__(BLOCK, 8) void knn_kernel(
    const float* __restrict__ query,
    const float* __restrict__ points,
    float* __restrict__ out)
{
    __shared__ float4 pts[2][CHUNK];       // 32 KB dbuf {x,y,z,-p2/2}
    __shared__ unsigned cand[ROWS][64];    // 4 KB candidate indices
    __shared__ unsigned scnt[ROWS];
    __shared__ float taub[ROWS][32];       // 2 KB: per-half top-16 lane-maxes

    const int tid  = threadIdx.x;
    const int lane = tid & 63;
    const int wv   = tid >> 6;             // 0..7
    const int g    = wv >> 1;              // row group 0..3
    const int h    = wv & 1;               // point-half 0/1
    const int bid  = blockIdx.x;           // 0..1023
    const int b    = bid >> 8;             // batch
    const int rb   = (bid & 255) * ROWS;   // first row of block

    const float* pb = points + b * (CC * NN);
    const float* qb = query  + b * (CC * MM);

    if (tid < ROWS) scnt[tid] = 0;

    // per-row query scalars (wave-uniform -> SGPRs) + exact reference q2
    float qx[RPW], qy[RPW], qz[RPW], q2[RPW], dm[RPW];
    #pragma unroll
    for (int r = 0; r < RPW; ++r) {
        int m = rb + g * RPW + r;
        float x = rfl(qb[m]);
        float y = rfl(qb[MM + m]);
        float z = rfl(qb[2*MM + m]);
        qx[r] = x; qy[r] = y; qz[r] = z;
        q2[r] = rfl(__fadd_rn(__fadd_rn(__fmul_rn(x,x), __fmul_rn(y,y)),
                              __fmul_rn(z,z)));
        dm[r] = -__builtin_inff();         // per-lane MAX of folded dot
    }

    // ---- staging: pack {x,y,z,-0.5*p2}; identical rounding both passes ----
    auto stage = [&](int ch, int bi) {
        #pragma unroll
        for (int i = 0; i < CHUNK / BLOCK; ++i) {   // 2 iters
            int ii = i * BLOCK + tid;
            int n  = ch * CHUNK + ii;
            float px = pb[n], py = pb[NN + n], pz = pb[2*NN + n];
            float p2 = __fadd_rn(__fadd_rn(__fmul_rn(px,px), __fmul_rn(py,py)),
                                 __fmul_rn(pz,pz));
            pts[bi][ii] = make_float4(px, py, pz, -0.5f * p2);
        }
    };

    // ---- Pass 1: per-lane per-row max folded dot over this wave's half ----
    auto comp1 = [&](int bi) {
        #pragma unroll
        for (int t = 0; t < HST; ++t) {
            float4 P = pts[bi][((h * HST + t) << 6) + lane];
            #pragma unroll
            for (int r = 0; r < RPW; ++r) {
                float dotf = __builtin_fmaf(qz[r], P.z,
                              __builtin_fmaf(qy[r], P.y,
                               __builtin_fmaf(qx[r], P.x, P.w)));
                dm[r] = fmaxf(dm[r], dotf);
            }
        }
    };

    stage(0, 0);
    #pragma unroll 1
    for (int ch = 0; ch < NCH; ch += 2) {
        __syncthreads();                       // buf0(ch) ready
        if (ch + 1 < NCH) stage(ch + 1, 1);
        comp1(0);
        __syncthreads();                       // buf1 ready; buf0 reads done
        if (ch + 2 < NCH) stage(ch + 2, 0);
        if (ch + 1 < NCH) comp1(1);
    }

    // ---- tau[row] = 16th largest of BOTH halves' lane-maxes (128 values,
    //      merged via per-half top-16 in LDS). Valid upper-bound filter. ----
    #pragma unroll
    for (int r = 0; r < RPW; ++r) {
        float v = dm[r];
        #pragma unroll
        for (int k = 2; k <= 64; k <<= 1) {
            #pragma unroll
            for (int j = k >> 1; j > 0; j >>= 1) {
                float o = __shfl_xor(v, j, 64);
                bool keepmin = (((lane & j) == 0) == ((lane & k) == 0));
                v = keepmin ? fminf(v, o) : fmaxf(v, o);
            }
        }
        if (lane >= 48) taub[g*RPW + r][h*16 + lane - 48] = v;  // top-16
    }
    __syncthreads();
    float rc[RPW];
    #pragma unroll
    for (int r = 0; r < RPW; ++r) {
        float v = (lane < 32) ? taub[g*RPW + r][lane] : -__builtin_inff();
        #pragma unroll
        for (int k = 2; k <= 64; k <<= 1) {
            #pragma unroll
            for (int j = k >> 1; j > 0; j >>= 1) {
                float o = __shfl_xor(v, j, 64);
                bool keepmin = (((lane & j) == 0) == ((lane & k) == 0));
                v = keepmin ? fminf(v, o) : fmaxf(v, o);
            }
        }
        float tau = __shfl(v, 48, 64);         // 16th largest of 32 reals
        rc[r] = rfl(tau - EPSD);
    }

    // ---- Pass 2: recompute folded dot on own half, collect candidates ----
    auto comp2 = [&](int ch, int bi) {
        #pragma unroll
        for (int t = 0; t < HST; ++t) {
            int st = h * HST + t;
            float4 P = pts[bi][(st << 6) + lane];
            unsigned n = (unsigned)(ch * CHUNK + (st << 6) + lane);
            #pragma unroll
            for (int r = 0; r < RPW; ++r) {
                float dotf = __builtin_fmaf(qz[r], P.z,
                              __builtin_fmaf(qy[r], P.y,
                               __builtin_fmaf(qx[r], P.x, P.w)));
                if (dotf >= rc[r]) {                     // rare
                    unsigned pos = atomicAdd(&scnt[g*RPW + r], 1u);
                    if (pos < 64u) cand[g*RPW + r][pos] = n;
                }
            }
        }
    };

    stage(0, 0);
    #pragma unroll 1
    for (int ch = 0; ch < NCH; ch += 2) {
        __syncthreads();
        if (ch + 1 < NCH) stage(ch + 1, 1);
        comp2(ch, 0);
        __syncthreads();
        if (ch + 2 < NCH) stage(ch + 2, 0);
        if (ch + 1 < NCH) comp2(ch + 1, 1);
    }
    __syncthreads();

    // ---- Epilogue: each wave handles local rows 2h, 2h+1 of its group ----
    #pragma unroll
    for (int rr = 0; rr < 2; ++rr) {
        int r   = 2*h + rr;                  // local row index (has q scalars)
        int row = g * RPW + r;
        unsigned c = scnt[row]; if (c > 64u) c = 64u;   // >=16 guaranteed
        unsigned kb = 0xffffffffu, id = 0xffffffffu;
        if (lane < (int)c) {
            id = cand[row][lane];
            float px = pb[id], py = pb[NN + id], pz = pb[2*NN + id];
            // bit-exact reference rounding (validated R3-R5):
            float p2 = __fadd_rn(__fadd_rn(__fmul_rn(px,px), __fmul_rn(py,py)),
                                 __fmul_rn(pz,pz));
            float dot = __builtin_fmaf(qz[r], pz,
                         __builtin_fmaf(qy[r], py, __fmul_rn(qx[r], px)));
            float d = __fsub_rn(__fadd_rn(q2[r], p2), __fmul_rn(2.0f, dot));
            unsigned fb = __float_as_uint(d);
            kb = (fb & 0x80000000u) ? ~fb : (fb | 0x80000000u);
        }
        #pragma unroll
        for (int k = 2; k <= 64; k <<= 1) {
            #pragma unroll
            for (int j = k >> 1; j > 0; j >>= 1) {
                unsigned ok = __shfl_xor(kb, j, 64);
                unsigned oi = __shfl_xor(id, j, 64);
                bool takeMin  = (((lane & j) == 0) == ((lane & k) == 0));
                bool selfLess = (kb < ok) || (kb == ok && id < oi);
                if (selfLess != takeMin) { kb = ok; id = oi; }
            }
        }
        if (lane < KK) {
            int m  = rb + row;
            int oi = (int)id;
            out[NP_OFF + (b * MM + m) * KK + lane] = (float)oi;
            out[((b * CC + 0) * MM + m) * KK + lane] = pb[oi];
            out[((b * CC + 1) * MM + m) * KK + lane] = pb[NN + oi];
            out[((b * CC + 2) * MM + m) * KK + lane] = pb[2*NN + oi];
        }
    }
}

extern "C" void kernel_launch(void* const* d_in, const int* in_sizes, int n_in,
                              void* d_out, int out_size, void* d_ws, size_t ws_size,
                              hipStream_t stream) {
    // d_in[0] = k (scalar, =16), d_in[1] = query f32 [4,3,4096],
    // d_in[2] = points f32 [4,3,8192]
    const float* query  = (const float*)d_in[1];
    const float* points = (const float*)d_in[2];
    float* out = (float*)d_out;
    dim3 grid(BQ * (MM / ROWS));    // 1024 blocks = 4/CU, 8 waves each
    dim3 block(BLOCK);
    knn_kernel<<<grid, block, 0, stream>>>(query, points, out);
}